// Round 1
// baseline (393.894 us; speedup 1.0000x reference)
//
#include <hip/hip_runtime.h>
#include <hip/hip_bf16.h>

#define N_FEAT 3072
#define LATENT 128
#define LOG2PI 1.8378770664093453f
#define NGB 512      // gemm blocks (blockIdx 1..512); block 0 = inverse

typedef __attribute__((ext_vector_type(8))) short short8;
typedef __attribute__((ext_vector_type(4))) float f32x4;

__device__ __forceinline__ unsigned short f2bf(float x) {
  unsigned int u = __float_as_uint(x);
  u += 0x7FFFu + ((u >> 16) & 1u);
  return (unsigned short)(u >> 16);
}

// ---------------------------------------------------------------------------
// k_prep: (a) Mp[b] = Wchunk^T Wchunk partial  (DIRECT store — no atomics)
//         (b) Wt[n][k] = bf16(W[k][n])
// 48 blocks x 64 k-rows; W read exactly once.
// ---------------------------------------------------------------------------
#define GR_CHUNK 64
__global__ __launch_bounds__(256) void k_prep(const float* __restrict__ W,
                                              float* __restrict__ Mp,
                                              unsigned short* __restrict__ Wt) {
  __shared__ __align__(16) float Ws[GR_CHUNK * 128];
  int t = threadIdx.x;
  int k0 = blockIdx.x * GR_CHUNK;
  const float* src = W + (size_t)k0 * 128;
#pragma unroll
  for (int c = 0; c < 8; ++c)
    ((float4*)Ws)[t + 256 * c] = ((const float4*)src)[t + 256 * c];
  __syncthreads();
  // --- gram partial: 8x8 register tiles ---
  int tr = t >> 4, tc = t & 15;
  float acc[8][8];
#pragma unroll
  for (int r = 0; r < 8; ++r)
#pragma unroll
    for (int c = 0; c < 8; ++c) acc[r][c] = 0.f;
#pragma unroll 2
  for (int k = 0; k < GR_CHUNK; ++k) {
    f32x4 a0 = *(f32x4*)&Ws[k * 128 + 8 * tr];
    f32x4 a1 = *(f32x4*)&Ws[k * 128 + 8 * tr + 4];
    f32x4 b0 = *(f32x4*)&Ws[k * 128 + 8 * tc];
    f32x4 b1 = *(f32x4*)&Ws[k * 128 + 8 * tc + 4];
    float av[8] = {a0.x, a0.y, a0.z, a0.w, a1.x, a1.y, a1.z, a1.w};
    float bv[8] = {b0.x, b0.y, b0.z, b0.w, b1.x, b1.y, b1.z, b1.w};
#pragma unroll
    for (int r = 0; r < 8; ++r)
#pragma unroll
      for (int c = 0; c < 8; ++c) acc[r][c] = fmaf(av[r], bv[c], acc[r][c]);
  }
  float* dst = Mp + (size_t)blockIdx.x * 16384 + (size_t)(8 * tr) * 128 + 8 * tc;
#pragma unroll
  for (int r = 0; r < 8; ++r) {
    *(f32x4*)(dst + r * 128) = (f32x4){acc[r][0], acc[r][1], acc[r][2], acc[r][3]};
    *(f32x4*)(dst + r * 128 + 4) = (f32x4){acc[r][4], acc[r][5], acc[r][6], acc[r][7]};
  }
  // --- Wt conversion: thread -> (col n, 32-k half) ---
  int n = t >> 1, h = t & 1;
  unsigned pk[16];
#pragma unroll
  for (int c = 0; c < 16; ++c)
    pk[c] = (unsigned)f2bf(Ws[(h * 32 + 2 * c) * 128 + n]) |
            ((unsigned)f2bf(Ws[(h * 32 + 2 * c + 1) * 128 + n]) << 16);
  uint4* wd = (uint4*)(Wt + (size_t)n * N_FEAT + k0 + h * 32);
#pragma unroll
  for (int c = 0; c < 4; ++c)
    wd[c] = make_uint4(pk[4 * c], pk[4 * c + 1], pk[4 * c + 2], pk[4 * c + 3]);
}

// ---------------------------------------------------------------------------
// k_red: M = sum of 48 gram partials (coalesced, ~1.5 us)
// ---------------------------------------------------------------------------
__global__ __launch_bounds__(256) void k_red(const float* __restrict__ Mp,
                                             float* __restrict__ M) {
  int i = blockIdx.x * 256 + threadIdx.x;
  float s = 0.f;
#pragma unroll
  for (int p = 0; p < 48; ++p) s += Mp[(size_t)p * 16384 + i];
  M[i] = s;
}

// ---------------------------------------------------------------------------
// k_gemm: block 0:      Gauss-Jordan inverse of M (+sigma^2 I), logdet, scalars
//         blocks 1..512: 16-row full-K tile, T = res*W direct store + sumsq.
// 256 threads, BK=64, double-buffered LDS, 1 barrier/iter, add-swizzled
// slots ((slot+row)&7) for conflict-free b128. LDS ~39KB -> 4 blocks/CU,
// so all 513 blocks co-resident; inverse (block 0) fully overlapped.
// ---------------------------------------------------------------------------
__global__ __launch_bounds__(256, 4) void k_gemm(
    const float* __restrict__ ex, const float* __restrict__ mean,
    const unsigned short* __restrict__ Wt, float* __restrict__ M,
    float* __restrict__ scal, const float* __restrict__ log_var,
    float* __restrict__ T, float* __restrict__ sumsq) {
  __shared__ __align__(16) unsigned short As[2][16][64];   // 4 KB
  __shared__ __align__(16) unsigned short Bs[2][128][64];  // 32 KB
  __shared__ float prow[2][128], pcol[2][128], dbuf[2], diag[128], red[2];
  int t = threadIdx.x;

  if (blockIdx.x == 0) {
    // ================= inverse path (all 256 threads) =================
    int itr = t >> 4, itc = t & 15;
    float lv = log_var[0];
    float sig2 = expf(lv);
    float a[8][8];
    {
      const float* srcM = M + (size_t)(8 * itr) * 128 + 8 * itc;
#pragma unroll
      for (int r = 0; r < 8; ++r) {
        f32x4 v0 = *(const f32x4*)(srcM + r * 128);
        f32x4 v1 = *(const f32x4*)(srcM + r * 128 + 4);
        a[r][0] = v0.x; a[r][1] = v0.y; a[r][2] = v0.z; a[r][3] = v0.w;
        a[r][4] = v1.x; a[r][5] = v1.y; a[r][6] = v1.z; a[r][7] = v1.w;
      }
      if (itr == itc) {
#pragma unroll
        for (int r = 0; r < 8; ++r) a[r][r] += sig2;
      }
      if (itr == 0) {
#pragma unroll
        for (int c = 0; c < 8; ++c) prow[0][8 * itc + c] = a[0][c];
      }
      if (itc == 0) {
#pragma unroll
        for (int r = 0; r < 8; ++r) pcol[0][8 * itr + r] = a[r][0];
      }
      if (t == 0) dbuf[0] = a[0][0];
    }
    __syncthreads();
    for (int kb = 0; kb < 16; ++kb) {
#pragma unroll
      for (int lk = 0; lk < 8; ++lk) {
        const int k = kb * 8 + lk;
        const int buf = k & 1;
        {
          float d = dbuf[buf];
          if (t == 0) diag[k] = d;
          float p = 1.0f / d;
          float pr[8], pc[8];
#pragma unroll
          for (int c = 0; c < 8; ++c) pr[c] = prow[buf][8 * itc + c] * p;
#pragma unroll
          for (int r = 0; r < 8; ++r) pc[r] = pcol[buf][8 * itr + r];
#pragma unroll
          for (int r = 0; r < 8; ++r)
#pragma unroll
            for (int c = 0; c < 8; ++c) a[r][c] = fmaf(-pc[r], pr[c], a[r][c]);
          bool myrow = (itr == (k >> 3));
          bool mycol = (itc == (k >> 3));
          if (myrow) {
#pragma unroll
            for (int c = 0; c < 8; ++c) a[lk][c] = pr[c];
          }
          if (mycol) {
#pragma unroll
            for (int r = 0; r < 8; ++r) a[r][lk] = -p * pc[r];
          }
          if (myrow && mycol) a[lk][lk] = p;
          if (k + 1 < 128) {
            const int nb = buf ^ 1;
            const int nl = (lk + 1) & 7;
            const int nr = (k + 1) >> 3;
            if (itr == nr) {
#pragma unroll
              for (int c = 0; c < 8; ++c) prow[nb][8 * itc + c] = a[nl][c];
            }
            if (itc == nr) {
#pragma unroll
              for (int r = 0; r < 8; ++r) pcol[nb][8 * itr + r] = a[r][nl];
            }
            if (itr == nr && itc == nr) dbuf[nb] = a[nl][nl];
          }
        }
        __syncthreads();
      }
    }
    {
      float* dst = M + (size_t)(8 * itr) * 128 + 8 * itc;
#pragma unroll
      for (int r = 0; r < 8; ++r) {
        f32x4 v0 = {a[r][0], a[r][1], a[r][2], a[r][3]};
        f32x4 v1 = {a[r][4], a[r][5], a[r][6], a[r][7]};
        *(f32x4*)(dst + r * 128) = v0;
        *(f32x4*)(dst + r * 128 + 4) = v1;
      }
    }
    float ld = 0.f;
    if (t < 128) ld = logf(diag[t]);
#pragma unroll
    for (int o = 1; o < 64; o <<= 1) ld += __shfl_xor(ld, o);
    if (t == 0) red[0] = ld;
    if (t == 64) red[1] = ld;
    __syncthreads();
    if (t == 0) {
      scal[0] = -0.5f * (N_FEAT * LOG2PI + (float)(N_FEAT - LATENT) * lv +
                         (red[0] + red[1]));
      scal[1] = expf(-lv);
    }
    return;
  }

  // ================= GEMM path: rows r0..r0+15, full K =================
  int r0 = (blockIdx.x - 1) * 16;

  // A staging: thread -> (row arow, 4-col group ag)
  int arow = t >> 4, ag = t & 15;
  const float* ep = ex + (size_t)(r0 + arow) * N_FEAT + ag * 4;
  const float* mp = mean + ag * 4;
  int awoff = arow * 128 + ((((ag >> 1) + arow) & 7) << 4) + (ag & 1) * 8;

  // B staging: thread -> (row brow, 32-col half bh), 4x16B each
  int brow = t >> 1, bh = t & 1;
  const unsigned short* wp = Wt + (size_t)brow * N_FEAT + bh * 32;
  int bwoff[4];
#pragma unroll
  for (int j = 0; j < 4; ++j)
    bwoff[j] = brow * 128 + ((((bh * 4 + j) + brow) & 7) << 4);

  // fragment read mapping: wave w -> cols w*32 .. w*32+31
  int lane = t & 63, w = t >> 6;
  int fr = lane & 15, fq = lane >> 4;
  int n0 = w * 32 + fr, n1 = n0 + 16;
  int aoff[2], boff0[2], boff1[2];
#pragma unroll
  for (int kk = 0; kk < 2; ++kk) {
    int s = kk * 4 + fq;
    aoff[kk]  = fr * 128 + (((s + fr) & 7) << 4);
    boff0[kk] = n0 * 128 + (((s + n0) & 7) << 4);
    boff1[kk] = n1 * 128 + (((s + n1) & 7) << 4);
  }

  f32x4 acc0 = {0.f, 0.f, 0.f, 0.f}, acc1 = {0.f, 0.f, 0.f, 0.f};
  float sq = 0.f;
  float4 e, m;
  uint4 g[4];

  auto pack_a = [&](char* dstA) {
    float rx = e.x - m.x, ry = e.y - m.y, rz = e.z - m.z, rw = e.w - m.w;
    sq = fmaf(rx, rx, sq); sq = fmaf(ry, ry, sq);
    sq = fmaf(rz, rz, sq); sq = fmaf(rw, rw, sq);
    uint2 pa;
    pa.x = (unsigned)f2bf(rx) | ((unsigned)f2bf(ry) << 16);
    pa.y = (unsigned)f2bf(rz) | ((unsigned)f2bf(rw) << 16);
    *(uint2*)(dstA + awoff) = pa;
  };
  auto write_b = [&](char* dstB) {
#pragma unroll
    for (int j = 0; j < 4; ++j) *(uint4*)(dstB + bwoff[j]) = g[j];
  };

  // prologue: tile 0 -> buffer 0
  e = *(const float4*)ep;
  m = *(const float4*)mp;
#pragma unroll
  for (int j = 0; j < 4; ++j) g[j] = *(const uint4*)(wp + j * 8);
  pack_a((char*)As);
  write_b((char*)Bs);
  __syncthreads();

#pragma unroll 2
  for (int it = 0; it < 48; ++it) {
    const int buf = it & 1;
    if (it + 1 < 48) {  // prefetch next tile into regs (latency hidden by MFMA)
      e = *(const float4*)(ep + (it + 1) * 64);
      m = *(const float4*)(mp + (it + 1) * 64);
      const unsigned short* wq = wp + (it + 1) * 64;
#pragma unroll
      for (int j = 0; j < 4; ++j) g[j] = *(const uint4*)(wq + j * 8);
    }
    char* Ar = (char*)As + buf * 2048;
    char* Br = (char*)Bs + buf * 16384;
#pragma unroll
    for (int kk = 0; kk < 2; ++kk) {
      short8 a  = *(const short8*)(Ar + aoff[kk]);
      short8 b0 = *(const short8*)(Br + boff0[kk]);
      short8 b1 = *(const short8*)(Br + boff1[kk]);
      acc0 = __builtin_amdgcn_mfma_f32_16x16x32_bf16(a, b0, acc0, 0, 0, 0);
      acc1 = __builtin_amdgcn_mfma_f32_16x16x32_bf16(a, b1, acc1, 0, 0, 0);
    }
    if (it + 1 < 48) {  // stage next tile into the other buffer
      pack_a((char*)As + (buf ^ 1) * 2048);
      write_b((char*)Bs + (buf ^ 1) * 16384);
    }
    __syncthreads();
    // single barrier/iter: writes target buf^1; buf is overwritten only
    // after the NEXT barrier (same proof as previous rounds)
  }

  // sumsq: reduce over the 16 ag-lanes of each row, direct store (no atomic)
  sq += __shfl_xor(sq, 1); sq += __shfl_xor(sq, 2);
  sq += __shfl_xor(sq, 4); sq += __shfl_xor(sq, 8);
  if (ag == 0) sumsq[r0 + arow] = sq;

  // T store: D layout col=lane&15, row=fq*4+reg — DIRECT (no atomics)
  float* tp = T + (size_t)(r0 + fq * 4) * 128 + w * 32 + fr;
#pragma unroll
  for (int ii = 0; ii < 4; ++ii) {
    tp[(size_t)ii * 128] = acc0[ii];
    tp[(size_t)ii * 128 + 16] = acc1[ii];
  }
}

// ---------------------------------------------------------------------------
// k_epi: 256 blocks x 32 rows: quad = t^T Minv t; out = scal0 - 0.5*scal1*
//        (sumsq - quad).  (round-2-proven epilogue, T staged from global)
// ---------------------------------------------------------------------------
__global__ __launch_bounds__(256) void k_epi(const float* __restrict__ T,
                                             const float* __restrict__ sumsq,
                                             const float* __restrict__ Minv,
                                             const float* __restrict__ scal,
                                             float* __restrict__ out) {
  __shared__ __align__(16) float Ts[32][132];
  __shared__ float rs[32];
  int t = threadIdx.x;
  int r0 = blockIdx.x * 32;
  int sr = t >> 3, sseg = t & 7;
  const float* tp = T + (size_t)(r0 + sr) * 128 + sseg * 16;
#pragma unroll
  for (int c = 0; c < 4; ++c) {
    float4 v = *(const float4*)(tp + c * 4);
    *(f32x4*)&Ts[sr][sseg * 16 + c * 4] = (f32x4){v.x, v.y, v.z, v.w};
  }
  if (t < 32) rs[t] = sumsq[r0 + t];
  __syncthreads();

  int rp = t >> 4, cg = t & 15;
  int ra = 2 * rp, rb = ra + 1;
  int c0 = cg * 8;
  float ya[8] = {0, 0, 0, 0, 0, 0, 0, 0};
  float yb[8] = {0, 0, 0, 0, 0, 0, 0, 0};
#pragma unroll 4
  for (int j = 0; j < 128; ++j) {
    float tav = Ts[ra][j];
    float tbv = Ts[rb][j];
    float4 v0 = *(const float4*)(Minv + j * LATENT + c0);
    float4 v1 = *(const float4*)(Minv + j * LATENT + c0 + 4);
    ya[0] = fmaf(tav, v0.x, ya[0]); ya[1] = fmaf(tav, v0.y, ya[1]);
    ya[2] = fmaf(tav, v0.z, ya[2]); ya[3] = fmaf(tav, v0.w, ya[3]);
    ya[4] = fmaf(tav, v1.x, ya[4]); ya[5] = fmaf(tav, v1.y, ya[5]);
    ya[6] = fmaf(tav, v1.z, ya[6]); ya[7] = fmaf(tav, v1.w, ya[7]);
    yb[0] = fmaf(tbv, v0.x, yb[0]); yb[1] = fmaf(tbv, v0.y, yb[1]);
    yb[2] = fmaf(tbv, v0.z, yb[2]); yb[3] = fmaf(tbv, v0.w, yb[3]);
    yb[4] = fmaf(tbv, v1.x, yb[4]); yb[5] = fmaf(tbv, v1.y, yb[5]);
    yb[6] = fmaf(tbv, v1.z, yb[6]); yb[7] = fmaf(tbv, v1.w, yb[7]);
  }
  float q0 = 0.f, q1 = 0.f;
#pragma unroll
  for (int c = 0; c < 8; ++c) {
    q0 = fmaf(ya[c], Ts[ra][c0 + c], q0);
    q1 = fmaf(yb[c], Ts[rb][c0 + c], q1);
  }
  q0 += __shfl_xor(q0, 1); q0 += __shfl_xor(q0, 2);
  q0 += __shfl_xor(q0, 4); q0 += __shfl_xor(q0, 8);
  q1 += __shfl_xor(q1, 1); q1 += __shfl_xor(q1, 2);
  q1 += __shfl_xor(q1, 4); q1 += __shfl_xor(q1, 8);
  if (cg == 0) {
    float cc = scal[0], is2 = scal[1];
    out[r0 + ra] = cc - 0.5f * is2 * (rs[ra] - q0);
    out[r0 + rb] = cc - 0.5f * is2 * (rs[rb] - q1);
  }
}

// ---------------------------------------------------------------------------
extern "C" void kernel_launch(void* const* d_in, const int* in_sizes, int n_in,
                              void* d_out, int out_size, void* d_ws, size_t ws_size,
                              hipStream_t stream) {
  (void)in_sizes; (void)n_in; (void)out_size; (void)ws_size;
  const float* ex   = (const float*)d_in[0];
  const float* W    = (const float*)d_in[1];
  const float* lv   = (const float*)d_in[2];
  const float* mean = (const float*)d_in[3];
  float* out = (float*)d_out;

  // ws: M(16384f) | scal(64f) | T(1048576f) | sumsq(8192f) | Wt(393216 bf16)
  // Mp (48*16384f = 786432f) ALIASES T: consumed by k_red before k_gemm writes T.
  float* M = (float*)d_ws;
  float* scal = M + 16384;
  float* T = scal + 64;
  float* sumsq = T + 1048576;
  unsigned short* Wt = (unsigned short*)(sumsq + 8192);
  float* Mp = T;

  // no memset needed: every buffer is fully written by its producer
  k_prep<<<48, 256, 0, stream>>>(W, Mp, Wt);
  k_red<<<64, 256, 0, stream>>>(Mp, M);
  k_gemm<<<NGB + 1, 256, 0, stream>>>(ex, mean, Wt, M, scal, lv, T, sumsq);
  k_epi<<<256, 256, 0, stream>>>(T, sumsq, M, scal, out);
}

// Round 5
// 212.689 us; speedup vs baseline: 1.8520x; 1.8520x over previous
//
#include <hip/hip_runtime.h>
#include <hip/hip_bf16.h>

#define N_FEAT 3072
#define LATENT 128
#define LOG2PI 1.8378770664093453f

typedef __attribute__((ext_vector_type(8))) short short8;
typedef __attribute__((ext_vector_type(4))) float f32x4;

__device__ __forceinline__ unsigned short f2bf(float x) {
  unsigned int u = __float_as_uint(x);
  u += 0x7FFFu + ((u >> 16) & 1u);
  return (unsigned short)(u >> 16);
}

typedef __attribute__((address_space(1))) const void gas_void;
typedef __attribute__((address_space(3))) void las_void;
__device__ __forceinline__ void gld_lds16(const void* g, void* s) {
  __builtin_amdgcn_global_load_lds((gas_void*)g, (las_void*)s, 16, 0, 0);
}

// ---------------------------------------------------------------------------
// k_prep: (a) Mp[b] = Wchunk^T Wchunk partial (direct store, no atomics)
//         (b) Wt[n][k] = bf16(W[k][n])        (round-1 proven)
// ---------------------------------------------------------------------------
#define GR_CHUNK 64
__global__ __launch_bounds__(256) void k_prep(const float* __restrict__ W,
                                              float* __restrict__ Mp,
                                              unsigned short* __restrict__ Wt) {
  __shared__ __align__(16) float Ws[GR_CHUNK * 128];
  int t = threadIdx.x;
  int k0 = blockIdx.x * GR_CHUNK;
  const float* src = W + (size_t)k0 * 128;
#pragma unroll
  for (int c = 0; c < 8; ++c)
    ((float4*)Ws)[t + 256 * c] = ((const float4*)src)[t + 256 * c];
  __syncthreads();
  int tr = t >> 4, tc = t & 15;
  float acc[8][8];
#pragma unroll
  for (int r = 0; r < 8; ++r)
#pragma unroll
    for (int c = 0; c < 8; ++c) acc[r][c] = 0.f;
#pragma unroll 2
  for (int k = 0; k < GR_CHUNK; ++k) {
    f32x4 a0 = *(f32x4*)&Ws[k * 128 + 8 * tr];
    f32x4 a1 = *(f32x4*)&Ws[k * 128 + 8 * tr + 4];
    f32x4 b0 = *(f32x4*)&Ws[k * 128 + 8 * tc];
    f32x4 b1 = *(f32x4*)&Ws[k * 128 + 8 * tc + 4];
    float av[8] = {a0.x, a0.y, a0.z, a0.w, a1.x, a1.y, a1.z, a1.w};
    float bv[8] = {b0.x, b0.y, b0.z, b0.w, b1.x, b1.y, b1.z, b1.w};
#pragma unroll
    for (int r = 0; r < 8; ++r)
#pragma unroll
      for (int c = 0; c < 8; ++c) acc[r][c] = fmaf(av[r], bv[c], acc[r][c]);
  }
  float* dst = Mp + (size_t)blockIdx.x * 16384 + (size_t)(8 * tr) * 128 + 8 * tc;
#pragma unroll
  for (int r = 0; r < 8; ++r) {
    *(f32x4*)(dst + r * 128) = (f32x4){acc[r][0], acc[r][1], acc[r][2], acc[r][3]};
    *(f32x4*)(dst + r * 128 + 4) = (f32x4){acc[r][4], acc[r][5], acc[r][6], acc[r][7]};
  }
  int n = t >> 1, h = t & 1;
  unsigned pk[16];
#pragma unroll
  for (int c = 0; c < 16; ++c)
    pk[c] = (unsigned)f2bf(Ws[(h * 32 + 2 * c) * 128 + n]) |
            ((unsigned)f2bf(Ws[(h * 32 + 2 * c + 1) * 128 + n]) << 16);
  uint4* wd = (uint4*)(Wt + (size_t)n * N_FEAT + k0 + h * 32);
#pragma unroll
  for (int c = 0; c < 4; ++c)
    wd[c] = make_uint4(pk[4 * c], pk[4 * c + 1], pk[4 * c + 2], pk[4 * c + 3]);
}

// ---------------------------------------------------------------------------
// k_red: M = sum of 48 gram partials (round-1 proven)
// ---------------------------------------------------------------------------
__global__ __launch_bounds__(256) void k_red(const float* __restrict__ Mp,
                                             float* __restrict__ M) {
  int i = blockIdx.x * 256 + threadIdx.x;
  float s = 0.f;
#pragma unroll
  for (int p = 0; p < 48; ++p) s += Mp[(size_t)p * 16384 + i];
  M[i] = s;
}

// ---------------------------------------------------------------------------
// k_gemm: block 0:       Gauss-Jordan inverse of M (+sigma^2 I), logdet
//         blocks 1..511: 32-row x BK=128 tile, split-K=2 (gid 255 covers both
//                        halves of its row group). 512 thr, 12 iters,
//                        double-buffered LDS, B via global_load_lds with
//                        pre-inverse-swizzled global source, RAW s_barrier +
//                        counted vmcnt(8): B DMAs span barriers (T3/T4-lite).
//                        Wave w owns B rows w*16..+15 for BOTH dma and read.
//         LDS = 80 KB -> 2 blocks/CU; grid 512 fully resident.
// ---------------------------------------------------------------------------
__global__ __launch_bounds__(512, 4) void k_gemm(
    const float* __restrict__ ex, const float* __restrict__ mean,
    const unsigned short* __restrict__ Wt, float* __restrict__ M,
    float* __restrict__ scal, const float* __restrict__ log_var,
    float* __restrict__ Tp, float* __restrict__ sqp, int direct) {
  __shared__ __align__(16) unsigned short As[2][32][128];   // 16 KB
  __shared__ __align__(16) unsigned short Bs[2][128][128];  // 64 KB
  int t = threadIdx.x;

  if (blockIdx.x == 0) {
    // ============ inverse path (threads 0..255 active), scratch in As ======
    float* sh = (float*)&As[0][0][0];
    float* PR = sh;        // prow[2][128]
    float* PC = sh + 256;  // pcol[2][128]
    float* DB = sh + 512;  // dbuf[2]
    float* DG = sh + 514;  // diag[128]
    float* RD = sh + 642;  // red[2]
    bool act = t < 256;
    int itr = t >> 4, itc = t & 15;
    float lv = log_var[0];
    float sig2 = expf(lv);
    float a[8][8];
    if (act) {
      const float* srcM = M + (size_t)(8 * itr) * 128 + 8 * itc;
#pragma unroll
      for (int r = 0; r < 8; ++r) {
        f32x4 v0 = *(const f32x4*)(srcM + r * 128);
        f32x4 v1 = *(const f32x4*)(srcM + r * 128 + 4);
        a[r][0] = v0.x; a[r][1] = v0.y; a[r][2] = v0.z; a[r][3] = v0.w;
        a[r][4] = v1.x; a[r][5] = v1.y; a[r][6] = v1.z; a[r][7] = v1.w;
      }
      if (itr == itc) {
#pragma unroll
        for (int r = 0; r < 8; ++r) a[r][r] += sig2;
      }
      if (itr == 0) {
#pragma unroll
        for (int c = 0; c < 8; ++c) PR[8 * itc + c] = a[0][c];
      }
      if (itc == 0) {
#pragma unroll
        for (int r = 0; r < 8; ++r) PC[8 * itr + r] = a[r][0];
      }
      if (t == 0) DB[0] = a[0][0];
    }
    __syncthreads();
    for (int kb = 0; kb < 16; ++kb) {
#pragma unroll
      for (int lk = 0; lk < 8; ++lk) {
        const int k = kb * 8 + lk;
        const int buf = k & 1;
        if (act) {
          float d = DB[buf];
          if (t == 0) DG[k] = d;
          float p = 1.0f / d;
          float pr[8], pc[8];
#pragma unroll
          for (int c = 0; c < 8; ++c) pr[c] = PR[buf * 128 + 8 * itc + c] * p;
#pragma unroll
          for (int r = 0; r < 8; ++r) pc[r] = PC[buf * 128 + 8 * itr + r];
#pragma unroll
          for (int r = 0; r < 8; ++r)
#pragma unroll
            for (int c = 0; c < 8; ++c) a[r][c] = fmaf(-pc[r], pr[c], a[r][c]);
          bool myrow = (itr == (k >> 3));
          bool mycol = (itc == (k >> 3));
          if (myrow) {
#pragma unroll
            for (int c = 0; c < 8; ++c) a[lk][c] = pr[c];
          }
          if (mycol) {
#pragma unroll
            for (int r = 0; r < 8; ++r) a[r][lk] = -p * pc[r];
          }
          if (myrow && mycol) a[lk][lk] = p;
          if (k + 1 < 128) {
            const int nb = buf ^ 1;
            const int nl = (lk + 1) & 7;
            const int nr = (k + 1) >> 3;
            if (itr == nr) {
#pragma unroll
              for (int c = 0; c < 8; ++c) PR[nb * 128 + 8 * itc + c] = a[nl][c];
            }
            if (itc == nr) {
#pragma unroll
              for (int r = 0; r < 8; ++r) PC[nb * 128 + 8 * itr + r] = a[r][nl];
            }
            if (itr == nr && itc == nr) DB[nb] = a[nl][nl];
          }
        }
        __syncthreads();
      }
    }
    if (act) {
      float* dst = M + (size_t)(8 * itr) * 128 + 8 * itc;
#pragma unroll
      for (int r = 0; r < 8; ++r) {
        f32x4 v0 = {a[r][0], a[r][1], a[r][2], a[r][3]};
        f32x4 v1 = {a[r][4], a[r][5], a[r][6], a[r][7]};
        *(f32x4*)(dst + r * 128) = v0;
        *(f32x4*)(dst + r * 128 + 4) = v1;
      }
    }
    float ld = 0.f;
    if (t < 128) ld = logf(DG[t]);
#pragma unroll
    for (int o = 1; o < 64; o <<= 1) ld += __shfl_xor(ld, o);
    if (t == 0) RD[0] = ld;
    if (t == 64) RD[1] = ld;
    __syncthreads();
    if (t == 0) {
      scal[0] = -0.5f * (N_FEAT * LOG2PI + (float)(N_FEAT - LATENT) * lv +
                         (RD[0] + RD[1]));
      scal[1] = expf(-lv);
    }
    return;
  }

  // ================= GEMM path =================
  int gid = (int)blockIdx.x - 1;        // 0..510
  int half = gid >> 8;                  // 0 or 1
  int rg = gid & 255;
  int r0 = rg * 32;
  const bool dual = (gid == 255);       // covers BOTH halves of rg 255
  const int NT = dual ? 24 : 12;
  const int tg0 = dual ? 0 : half * 12;

  int lane = t & 63, w = t >> 6;

  // ---- A staging: thread -> (row arow, 8-col group ag), swizzled 16B slot --
  int arow = t >> 4, ag = t & 15;
  const float* ep = ex + (size_t)(r0 + arow) * N_FEAT + (size_t)tg0 * 128 + ag * 8;
  const float* mp = mean + (size_t)tg0 * 128 + ag * 8;
  int awoff = arow * 256 + ((ag & 8) + ((ag + arow) & 7)) * 16;

  // ---- B DMA: wave w owns rows w*16..w*16+15; source pre-inverse-swizzled --
  int sp = lane & 15, rl = lane >> 4;
  const unsigned short* bsrc[4];
#pragma unroll
  for (int j = 0; j < 4; ++j) {
    int n = w * 16 + j * 4 + rl;
    int s = (sp & 8) | ((sp - n) & 7);
    bsrc[j] = Wt + (size_t)n * N_FEAT + (size_t)tg0 * 128 + s * 8;
  }
  char* ldsB0 = (char*)Bs + (size_t)w * 4096;           // wave-uniform dests
  char* ldsB1 = (char*)Bs + 32768 + (size_t)w * 4096;

  // ---- fragment read offsets (swizzled) ----
  int fr = lane & 15, fq = lane >> 4;
  int aoff0[4], aoff1[4], boff[4];
#pragma unroll
  for (int kk = 0; kk < 4; ++kk) {
    int sI = kk * 4 + fq;
    aoff0[kk] = fr * 256 + ((sI & 8) + ((sI + fr) & 7)) * 16;
    int ar1 = 16 + fr;
    aoff1[kk] = ar1 * 256 + ((sI & 8) + ((sI + ar1) & 7)) * 16;
    int n = w * 16 + fr;
    boff[kk] = n * 256 + ((sI & 8) + ((sI + n) & 7)) * 16;
  }

  f32x4 acc0 = {0.f, 0.f, 0.f, 0.f}, acc1 = {0.f, 0.f, 0.f, 0.f};
  float sq = 0.f;
  float4 e, e2, m, m2;

  auto issueA = [&](int it) {
    const float* p = ep + (size_t)it * 128;
    const float* q = mp + (size_t)it * 128;
    e  = *(const float4*)p;       e2 = *(const float4*)(p + 4);
    m  = *(const float4*)q;       m2 = *(const float4*)(q + 4);
  };
  auto issueB = [&](int it, int bufN) {
    char* d = bufN ? ldsB1 : ldsB0;
#pragma unroll
    for (int j = 0; j < 4; ++j)
      gld_lds16(bsrc[j] + (size_t)it * 128, d + j * 1024);
  };
  auto packA = [&](int bufN) {
    float r0_ = e.x - m.x,   r1_ = e.y - m.y,   r2_ = e.z - m.z,   r3_ = e.w - m.w;
    float r4_ = e2.x - m2.x, r5_ = e2.y - m2.y, r6_ = e2.z - m2.z, r7_ = e2.w - m2.w;
    sq = fmaf(r0_, r0_, sq); sq = fmaf(r1_, r1_, sq);
    sq = fmaf(r2_, r2_, sq); sq = fmaf(r3_, r3_, sq);
    sq = fmaf(r4_, r4_, sq); sq = fmaf(r5_, r5_, sq);
    sq = fmaf(r6_, r6_, sq); sq = fmaf(r7_, r7_, sq);
    uint4 pa;
    pa.x = (unsigned)f2bf(r0_) | ((unsigned)f2bf(r1_) << 16);
    pa.y = (unsigned)f2bf(r2_) | ((unsigned)f2bf(r3_) << 16);
    pa.z = (unsigned)f2bf(r4_) | ((unsigned)f2bf(r5_) << 16);
    pa.w = (unsigned)f2bf(r6_) | ((unsigned)f2bf(r7_) << 16);
    *(uint4*)((char*)As + bufN * 8192 + awoff) = pa;
  };
  auto mma = [&](int bufN) {
    char* Ab = (char*)As + bufN * 8192;
    char* Bb = (char*)Bs + bufN * 32768;
#pragma unroll
    for (int kk = 0; kk < 4; ++kk) {
      short8 a0 = *(const short8*)(Ab + aoff0[kk]);
      short8 a1 = *(const short8*)(Ab + aoff1[kk]);
      short8 b  = *(const short8*)(Bb + boff[kk]);
      acc0 = __builtin_amdgcn_mfma_f32_16x16x32_bf16(a0, b, acc0, 0, 0, 0);
      acc1 = __builtin_amdgcn_mfma_f32_16x16x32_bf16(a1, b, acc1, 0, 0, 0);
    }
  };

  // ---- prologue: stage tile0 into buf0 ----
  issueA(0);
  __builtin_amdgcn_sched_barrier(0);
  issueB(0, 0);
  packA(0);                                   // compiler waits the A regs
  asm volatile("s_waitcnt lgkmcnt(0)" ::: "memory");
  __builtin_amdgcn_s_barrier();
  __builtin_amdgcn_sched_barrier(0);

  // ---- main loop: counted vmcnt lets B-DMA span barriers ----
  for (int it = 0; it < NT - 1; ++it) {
    const int buf = it & 1;
    issueA(it + 1);                           // A regs issued FIRST (older)
    __builtin_amdgcn_sched_barrier(0);        // pin order: A before B-DMA
    issueB(it + 1, buf ^ 1);
    // outstanding: B(it)=4 oldest, A(it+1)=4, B(it+1)=4 -> wait oldest 4 only
    asm volatile("s_waitcnt vmcnt(8)" ::: "memory");
    __builtin_amdgcn_sched_barrier(0);
    mma(buf);
    packA(buf ^ 1);                           // waits A(it+1) via vmcnt(4)
    asm volatile("s_waitcnt lgkmcnt(0)" ::: "memory");
    __builtin_amdgcn_s_barrier();
    __builtin_amdgcn_sched_barrier(0);
  }
  asm volatile("s_waitcnt vmcnt(0)" ::: "memory");
  __builtin_amdgcn_sched_barrier(0);
  mma((NT - 1) & 1);

  // ---- sumsq: reduce over 16 ag-lanes of each row ----
  sq += __shfl_xor(sq, 1); sq += __shfl_xor(sq, 2);
  sq += __shfl_xor(sq, 4); sq += __shfl_xor(sq, 8);

  if (direct) {
    if (ag == 0) sqp[half * 8192 + r0 + arow] = sq;
    float* tp = Tp + (size_t)half * 1048576 +
                (size_t)(r0 + fq * 4) * 128 + w * 16 + fr;
#pragma unroll
    for (int ii = 0; ii < 4; ++ii) {
      tp[(size_t)ii * 128] = acc0[ii];          // rows fq*4+ii
      tp[(size_t)ii * 128 + 2048] = acc1[ii];   // rows 16+fq*4+ii
    }
    if (dual) {  // half-1 partials of rg 255 never produced: zero them
      float* z = Tp + 1048576 + (size_t)r0 * 128;
      for (int i = t; i < 1024; i += 512) ((f32x4*)z)[i] = (f32x4){0, 0, 0, 0};
      if (t < 32) sqp[8192 + r0 + t] = 0.f;
    }
  } else {
    if (ag == 0) atomicAdd(&sqp[r0 + arow], sq);
    float* tp = Tp + (size_t)(r0 + fq * 4) * 128 + w * 16 + fr;
#pragma unroll
    for (int ii = 0; ii < 4; ++ii) {
      atomicAdd(tp + (size_t)ii * 128, acc0[ii]);
      atomicAdd(tp + (size_t)ii * 128 + 2048, acc1[ii]);
    }
  }
}

// ---------------------------------------------------------------------------
// k_epi: 256 blocks x 32 rows: t = Tp0(+Tp1); quad = t^T Minv t;
//        out = scal0 - 0.5*scal1*(sumsq - quad)
// ---------------------------------------------------------------------------
__global__ __launch_bounds__(256) void k_epi(const float* __restrict__ Tp,
                                             const float* __restrict__ sqp,
                                             const float* __restrict__ Minv,
                                             const float* __restrict__ scal,
                                             float* __restrict__ out, int two) {
  __shared__ __align__(16) float Ts[32][132];
  __shared__ float rs[32];
  int t = threadIdx.x;
  int r0 = blockIdx.x * 32;
  int sr = t >> 3, sseg = t & 7;
  const float* tp0 = Tp + (size_t)(r0 + sr) * 128 + sseg * 16;
#pragma unroll
  for (int c = 0; c < 4; ++c) {
    float4 v0 = *(const float4*)(tp0 + c * 4);
    if (two) {
      float4 v1 = *(const float4*)(tp0 + 1048576 + c * 4);
      v0.x += v1.x; v0.y += v1.y; v0.z += v1.z; v0.w += v1.w;
    }
    *(f32x4*)&Ts[sr][sseg * 16 + c * 4] = (f32x4){v0.x, v0.y, v0.z, v0.w};
  }
  if (t < 32) rs[t] = two ? (sqp[r0 + t] + sqp[8192 + r0 + t]) : sqp[r0 + t];
  __syncthreads();

  int rp = t >> 4, cg = t & 15;
  int ra = 2 * rp, rb = ra + 1;
  int c0 = cg * 8;
  float ya[8] = {0, 0, 0, 0, 0, 0, 0, 0};
  float yb[8] = {0, 0, 0, 0, 0, 0, 0, 0};
#pragma unroll 4
  for (int j = 0; j < 128; ++j) {
    float tav = Ts[ra][j];
    float tbv = Ts[rb][j];
    float4 v0 = *(const float4*)(Minv + j * LATENT + c0);
    float4 v1 = *(const float4*)(Minv + j * LATENT + c0 + 4);
    ya[0] = fmaf(tav, v0.x, ya[0]); ya[1] = fmaf(tav, v0.y, ya[1]);
    ya[2] = fmaf(tav, v0.z, ya[2]); ya[3] = fmaf(tav, v0.w, ya[3]);
    ya[4] = fmaf(tav, v1.x, ya[4]); ya[5] = fmaf(tav, v1.y, ya[5]);
    ya[6] = fmaf(tav, v1.z, ya[6]); ya[7] = fmaf(tav, v1.w, ya[7]);
    yb[0] = fmaf(tbv, v0.x, yb[0]); yb[1] = fmaf(tbv, v0.y, yb[1]);
    yb[2] = fmaf(tbv, v0.z, yb[2]); yb[3] = fmaf(tbv, v0.w, yb[3]);
    yb[4] = fmaf(tbv, v1.x, yb[4]); yb[5] = fmaf(tbv, v1.y, yb[5]);
    yb[6] = fmaf(tbv, v1.z, yb[6]); yb[7] = fmaf(tbv, v1.w, yb[7]);
  }
  float q0 = 0.f, q1 = 0.f;
#pragma unroll
  for (int c = 0; c < 8; ++c) {
    q0 = fmaf(ya[c], Ts[ra][c0 + c], q0);
    q1 = fmaf(yb[c], Ts[rb][c0 + c], q1);
  }
  q0 += __shfl_xor(q0, 1); q0 += __shfl_xor(q0, 2);
  q0 += __shfl_xor(q0, 4); q0 += __shfl_xor(q0, 8);
  q1 += __shfl_xor(q1, 1); q1 += __shfl_xor(q1, 2);
  q1 += __shfl_xor(q1, 4); q1 += __shfl_xor(q1, 8);
  if (cg == 0) {
    float cc = scal[0], is2 = scal[1];
    out[r0 + ra] = cc - 0.5f * is2 * (rs[ra] - q0);
    out[r0 + rb] = cc - 0.5f * is2 * (rs[rb] - q1);
  }
}

// ---------------------------------------------------------------------------
extern "C" void kernel_launch(void* const* d_in, const int* in_sizes, int n_in,
                              void* d_out, int out_size, void* d_ws, size_t ws_size,
                              hipStream_t stream) {
  (void)in_sizes; (void)n_in; (void)out_size;
  const float* ex   = (const float*)d_in[0];
  const float* W    = (const float*)d_in[1];
  const float* lv   = (const float*)d_in[2];
  const float* mean = (const float*)d_in[3];
  float* out = (float*)d_out;

  // direct layout: M(16384) | scal(64) | Tp(2x1048576) | sqp(2x16384/2) | Wt
  //   total = 9,306,368 B.  Mp aliases Tp (consumed by k_red first).
  // atomic fallback (proven 5,079,296 B): M | scal | T(1048576) | sumsq | Wt.
  const size_t need_direct = (size_t)(16384 + 64 + 2097152 + 16384 + 196608) * 4;
  int direct = (ws_size >= need_direct) ? 1 : 0;

  float* M = (float*)d_ws;
  float* scal = M + 16384;
  float* Tp = scal + 64;
  float* sqp;
  unsigned short* Wt;
  if (direct) {
    sqp = Tp + 2097152;
    Wt = (unsigned short*)(sqp + 16384);
  } else {
    sqp = Tp + 1048576;
    Wt = (unsigned short*)(sqp + 8192);
  }
  float* Mp = Tp;  // gram partials alias Tp; consumed before k_gemm writes Tp

  k_prep<<<48, 256, 0, stream>>>(W, Mp, Wt);
  k_red<<<64, 256, 0, stream>>>(Mp, M);
  if (!direct)  // atomics need zeroed T+sumsq; must come AFTER k_red (alias)
    hipMemsetAsync(Tp, 0, (size_t)(1048576 + 8192) * sizeof(float), stream);
  k_gemm<<<512, 512, 0, stream>>>(ex, mean, Wt, M, scal, lv, Tp, sqp, direct);
  k_epi<<<256, 256, 0, stream>>>(Tp, sqp, M, scal, out, direct ? 1 : 0);
}